// Round 2
// baseline (273.964 us; speedup 1.0000x reference)
//
#include <hip/hip_runtime.h>

#define N_BLOCKS 12
#define D 256
#define BATCH 8192

typedef __attribute__((ext_vector_type(8))) short bf16x8;   // 8 bf16 = 4 VGPRs
typedef __attribute__((ext_vector_type(4))) float f32x4;

// fp32 -> bf16 round-to-nearest-even (bit trick; inputs are finite)
__device__ __forceinline__ unsigned short f2bf(float f) {
  unsigned int u = __float_as_uint(f);
  u += 0x7fffu + ((u >> 16) & 1u);
  return (unsigned short)(u >> 16);
}

// async global->LDS, 16B per lane. LDS dest = wave-uniform base + lane*16.
__device__ __forceinline__ void gld16(const unsigned short* g, unsigned short* l) {
  __builtin_amdgcn_global_load_lds(
      (const __attribute__((address_space(1))) unsigned int*)g,
      (__attribute__((address_space(3))) unsigned int*)l,
      16, 0, 0);
}

// ---------------- Pass 1a: X fp32 -> bf16 (straight copy-convert) ----------
__global__ void cvt_x(const float* __restrict__ X, unsigned short* __restrict__ Xb) {
  const long long t = (long long)blockIdx.x * 256 + threadIdx.x;
  const long long base = t * 8;
  const float4 v0 = *(const float4*)(X + base);
  const float4 v1 = *(const float4*)(X + base + 4);
  uint4 r;
  r.x = (unsigned)f2bf(v0.x) | ((unsigned)f2bf(v0.y) << 16);
  r.y = (unsigned)f2bf(v0.z) | ((unsigned)f2bf(v0.w) << 16);
  r.z = (unsigned)f2bf(v1.x) | ((unsigned)f2bf(v1.y) << 16);
  r.w = (unsigned)f2bf(v1.z) | ((unsigned)f2bf(v1.w) << 16);
  *(uint4*)(Xb + base) = r;
}

// ------------- Pass 1b: W[k][i][o] fp32 -> Wt[k][o][i] bf16 (LDS transpose) -
__global__ void cvt_w(const float* __restrict__ W, unsigned short* __restrict__ Wt) {
  __shared__ unsigned short tile[32][33];   // +1 pad vs bank conflicts
  const int k  = blockIdx.x >> 6;
  const int t  = blockIdx.x & 63;
  const int ti = t >> 3;                    // tile row (i dim), 8 tiles
  const int tj = t & 7;                     // tile col (o dim)
  const float* Wk = W + (long long)k * D * D;
  unsigned short* Wtk = Wt + (long long)k * D * D;
  const int lx = threadIdx.x & 31, ly = threadIdx.x >> 5;   // 32x8
  #pragma unroll
  for (int r = 0; r < 4; ++r) {
    const int i = ti * 32 + ly + r * 8;
    const int o = tj * 32 + lx;
    tile[ly + r * 8][lx] = f2bf(Wk[i * D + o]);
  }
  __syncthreads();
  #pragma unroll
  for (int r = 0; r < 4; ++r) {
    const int o = tj * 32 + ly + r * 8;
    const int i = ti * 32 + lx;
    Wtk[o * D + i] = tile[lx][ly + r * 8];
  }
}

// ------------- Pass 2: block-sparse GEMM, BM=BN=128, BK=32 -----------------
// Per output row i: Y[i] = sum_t Xb[j_t] @ W[k_t] + sum_t b[k_t]
// 4 waves; wave (wr,wc) owns a 64x64 subtile = 4x4 mfma_f32_16x16x32_bf16.
// LDS layout is XOR-swizzled: 16B chunk c of row r lives at slot c^((r>>1)&3)
// -> fragment ds_read_b128 aliasing drops from 8-way to 2-way (free, m136).
// Legal with global_load_lds because only the LDS side is lane-contiguous;
// each lane fetches the global chunk belonging at its slot.
__launch_bounds__(256)
__global__ void bs_gemm(const unsigned short* __restrict__ Xb,
                        const unsigned short* __restrict__ Wt,
                        const float* __restrict__ bias,
                        const int* __restrict__ i_idx,
                        const int* __restrict__ j_idx,
                        int nact,
                        float* __restrict__ Y) {
  __shared__ unsigned short sA[128 * 32];   // A[m][k], swizzled chunks (8 KB)
  __shared__ unsigned short sB[128 * 32];   // B stored [n][k], swizzled

  const int bid = blockIdx.x;
  const int i   = bid >> 7;        // output row (12)
  const int rem = bid & 127;
  const int bm  = rem >> 1;        // 64 M-tiles
  const int bn  = rem & 1;         // 2 N-tiles

  // collect active blocks feeding output row i (pattern gives 4)
  int ks[8], js[8], nk = 0;
  for (int k = 0; k < nact; ++k)
    if (i_idx[k] == i && nk < 8) { ks[nk] = k; js[nk] = j_idx[k]; ++nk; }

  const int tid  = threadIdx.x;
  const int wave = tid >> 6;
  const int lane = tid & 63;
  const int wr   = wave >> 1, wc = wave & 1;

  // ---- staging: thread stages slots L and L+256 of each 512-chunk region.
  // slot L -> row r=L>>2, stored chunk c_st=L&3, global chunk c_g=c_st^((r>>1)&3)
  const int L1 = tid, L2 = tid + 256;
  const int r1 = L1 >> 2, c1 = (L1 & 3) ^ ((r1 >> 1) & 3);
  const int r2 = L2 >> 2, c2 = (L2 & 3) ^ ((r2 >> 1) & 3);
  const int g1 = r1 * D + c1 * 8;          // global elem offset (row-major, ld=D)
  const int g2 = r2 * D + c2 * 8;
  unsigned short* lA1 = sA + L1 * 8;
  unsigned short* lA2 = sA + L2 * 8;
  unsigned short* lB1 = sB + L1 * 8;
  unsigned short* lB2 = sB + L2 * 8;

  // ---- fragment read offsets (swizzle sel is invariant under row+=16)
  const int q      = lane >> 4;            // k-quad
  const int a_row  = wr * 64 + (lane & 15);
  const int b_row  = wc * 64 + (lane & 15);
  const int a_sw   = (q ^ ((a_row >> 1) & 3)) * 8;   // elem offset of chunk
  const int b_sw   = (q ^ ((b_row >> 1) & 3)) * 8;

  f32x4 acc[4][4] = {};

  for (int t = 0; t < nk; ++t) {
    const unsigned short* Ab = Xb + ((long long)js[t] * BATCH + bm * 128) * D;
    const unsigned short* Bb = Wt + ((long long)ks[t] * D + bn * 128) * D;
    #pragma unroll
    for (int d0 = 0; d0 < D; d0 += 32) {
      gld16(Ab + g1 + d0, lA1);
      gld16(Ab + g2 + d0, lA2);
      gld16(Bb + g1 + d0, lB1);
      gld16(Bb + g2 + d0, lB2);
      __syncthreads();   // drains vmcnt: staging complete

      bf16x8 aF[4], bF[4];
      #pragma unroll
      for (int mt = 0; mt < 4; ++mt)
        aF[mt] = *(const bf16x8*)(sA + (a_row + mt * 16) * 32 + a_sw);
      #pragma unroll
      for (int nt = 0; nt < 4; ++nt)
        bF[nt] = *(const bf16x8*)(sB + (b_row + nt * 16) * 32 + b_sw);
      #pragma unroll
      for (int mt = 0; mt < 4; ++mt)
        #pragma unroll
        for (int nt = 0; nt < 4; ++nt)
          acc[mt][nt] = __builtin_amdgcn_mfma_f32_16x16x32_bf16(
              aF[mt], bF[nt], acc[mt][nt], 0, 0, 0);
      __syncthreads();   // all reads done before next staging overwrites
    }
  }

  // epilogue: C/D layout col=lane&15, row=quad*4+reg; bias folded here
  float* Yb = Y + (long long)i * BATCH * D;
  const int m0 = bm * 128 + wr * 64 + (q * 4);
  const int n0 = bn * 128 + wc * 64 + (lane & 15);
  float bsum[4];
  #pragma unroll
  for (int nt = 0; nt < 4; ++nt) {
    float s = 0.f;
    for (int t = 0; t < nk; ++t) s += bias[ks[t] * D + n0 + nt * 16];
    bsum[nt] = s;
  }
  #pragma unroll
  for (int nt = 0; nt < 4; ++nt) {
    #pragma unroll
    for (int mt = 0; mt < 4; ++mt)
      #pragma unroll
      for (int r = 0; r < 4; ++r)
        Yb[(long long)(m0 + mt * 16 + r) * D + (n0 + nt * 16)] = acc[mt][nt][r] + bsum[nt];
  }
}

extern "C" void kernel_launch(void* const* d_in, const int* in_sizes, int n_in,
                              void* d_out, int out_size, void* d_ws, size_t ws_size,
                              hipStream_t stream) {
  const float* X = (const float*)d_in[0];
  const float* W = (const float*)d_in[1];
  const float* b = (const float*)d_in[2];
  const int* i_idx = (const int*)d_in[3];
  const int* j_idx = (const int*)d_in[4];
  float* Y = (float*)d_out;
  const int nact = in_sizes[3];   // 48

  // workspace layout: Xb (48 MB bf16) | Wt (6 MB bf16, transposed)
  unsigned short* Xb = (unsigned short*)d_ws;
  unsigned short* Wt = (unsigned short*)((char*)d_ws + (size_t)N_BLOCKS * BATCH * D * 2);

  cvt_x<<<(N_BLOCKS * BATCH * D) / (256 * 8), 256, 0, stream>>>(X, Xb);
  cvt_w<<<nact * 64, 256, 0, stream>>>(W, Wt);
  bs_gemm<<<N_BLOCKS * 64 * 2, 256, 0, stream>>>(Xb, Wt, b, i_idx, j_idx, nact, Y);
}

// Round 3
// 271.580 us; speedup vs baseline: 1.0088x; 1.0088x over previous
//
#include <hip/hip_runtime.h>

#define N_BLOCKS 12
#define D 256
#define BATCH 8192

typedef __attribute__((ext_vector_type(8))) short bf16x8;   // 8 bf16 = 4 VGPRs
typedef __attribute__((ext_vector_type(4))) float f32x4;

// fp32 -> bf16 round-to-nearest-even (bit trick; inputs are finite)
__device__ __forceinline__ unsigned short f2bf(float f) {
  unsigned int u = __float_as_uint(f);
  u += 0x7fffu + ((u >> 16) & 1u);
  return (unsigned short)(u >> 16);
}

// async global->LDS, 16B per lane. LDS dest = wave-uniform base + lane*16.
__device__ __forceinline__ void gld16(const unsigned short* g, unsigned short* l) {
  __builtin_amdgcn_global_load_lds(
      (const __attribute__((address_space(1))) unsigned int*)g,
      (__attribute__((address_space(3))) unsigned int*)l,
      16, 0, 0);
}

// ---------------- Pass 1a: X fp32 -> bf16 (straight copy-convert) ----------
__global__ void cvt_x(const float* __restrict__ X, unsigned short* __restrict__ Xb) {
  const long long t = (long long)blockIdx.x * 256 + threadIdx.x;
  const long long base = t * 8;
  const float4 v0 = *(const float4*)(X + base);
  const float4 v1 = *(const float4*)(X + base + 4);
  uint4 r;
  r.x = (unsigned)f2bf(v0.x) | ((unsigned)f2bf(v0.y) << 16);
  r.y = (unsigned)f2bf(v0.z) | ((unsigned)f2bf(v0.w) << 16);
  r.z = (unsigned)f2bf(v1.x) | ((unsigned)f2bf(v1.y) << 16);
  r.w = (unsigned)f2bf(v1.z) | ((unsigned)f2bf(v1.w) << 16);
  *(uint4*)(Xb + base) = r;
}

// ------------- Pass 1b: W[k][i][o] fp32 -> Wt[k][o][i] bf16 (LDS transpose) -
__global__ void cvt_w(const float* __restrict__ W, unsigned short* __restrict__ Wt) {
  __shared__ unsigned short tile[32][33];   // +1 pad vs bank conflicts
  const int k  = blockIdx.x >> 6;
  const int t  = blockIdx.x & 63;
  const int ti = t >> 3;                    // tile row (i dim), 8 tiles
  const int tj = t & 7;                     // tile col (o dim)
  const float* Wk = W + (long long)k * D * D;
  unsigned short* Wtk = Wt + (long long)k * D * D;
  const int lx = threadIdx.x & 31, ly = threadIdx.x >> 5;   // 32x8
  #pragma unroll
  for (int r = 0; r < 4; ++r) {
    const int i = ti * 32 + ly + r * 8;
    const int o = tj * 32 + lx;
    tile[ly + r * 8][lx] = f2bf(Wk[i * D + o]);
  }
  __syncthreads();
  #pragma unroll
  for (int r = 0; r < 4; ++r) {
    const int o = tj * 32 + ly + r * 8;
    const int i = ti * 32 + lx;
    Wtk[o * D + i] = tile[lx][ly + r * 8];
  }
}

// ------------- Pass 2: block-sparse GEMM, BM=BN=128, BK=32, LDS dbuf -------
// Per output row i: Y[i] = sum_t Xb[j_t] @ W[k_t] + sum_t b[k_t]
// 4 waves; wave (wr,wc) owns a 64x64 subtile = 4x4 mfma_f32_16x16x32_bf16.
// Pipeline: ONE barrier per K-iter; staging for iter u+1 issued right after
// the barrier into the alternate LDS buffer, so the global_load_lds has the
// whole compute phase of iter u in flight before the next barrier drains it.
// Linear (non-swizzled) staging: round 2 showed the XOR swizzle slowed
// staging coalescing; the ds_read conflicts it removed were latency-hidden.
__launch_bounds__(256)
__global__ void bs_gemm(const unsigned short* __restrict__ Xb,
                        const unsigned short* __restrict__ Wt,
                        const float* __restrict__ bias,
                        const int* __restrict__ i_idx,
                        const int* __restrict__ j_idx,
                        int nact,
                        float* __restrict__ Y) {
  // [A buf0 | A buf1 | B buf0 | B buf1], each 128x32 bf16 = 8 KB (32 KB total)
  __shared__ unsigned short sm[4 * 4096];

  const int bid = blockIdx.x;
  const int i   = bid >> 7;        // output row (12)
  const int rem = bid & 127;
  const int bm  = rem >> 1;        // 64 M-tiles
  const int bn  = rem & 1;         // 2 N-tiles

  // collect active blocks feeding output row i (pattern gives exactly 4)
  int ks[4], js[4], nk = 0;
  for (int k = 0; k < nact; ++k)
    if (i_idx[k] == i && nk < 4) { ks[nk] = k; js[nk] = j_idx[k]; ++nk; }

  const int tid  = threadIdx.x;
  const int wave = tid >> 6;
  const int lane = tid & 63;
  const int wr   = wave >> 1, wc = wave & 1;

  // staging: thread stages 16B at row=tid/4 (stride D), chunk=(tid&3)*8 elems
  const int g_off = (tid >> 2) * D + (tid & 3) * 8;

  // per-tile global base pointers (compile-time indexed after full unroll)
  const unsigned short* At[4];
  const unsigned short* Bt[4];
  #pragma unroll
  for (int t = 0; t < 4; ++t) {
    At[t] = Xb + ((long long)js[t] * BATCH + bm * 128) * D + g_off;
    Bt[t] = Wt + ((long long)ks[t] * D + bn * 128) * D + g_off;
  }

  // fragment read offsets
  const int q      = lane >> 4;            // k-quad
  const int frag_k = q * 8;
  const int a_row  = wr * 64 + (lane & 15);
  const int b_row  = wc * 64 + (lane & 15);

  f32x4 acc[4][4] = {};

  // prologue: stage iter 0 into buffer 0
  {
    unsigned short* lA = sm + tid * 8;
    unsigned short* lB = sm + 2 * 4096 + tid * 8;
    gld16(At[0], lA);
    gld16(At[0] + 64 * D, lA + 2048);
    gld16(Bt[0], lB);
    gld16(Bt[0] + 64 * D, lB + 2048);
  }

  // 32 flattened K-iters: iter u = tile (u>>3), k-offset (u&7)*32
  #pragma unroll
  for (int u = 0; u < 32; ++u) {
    const int p = u & 1;
    __syncthreads();   // vmcnt: buf[p] staged; lgkmcnt: buf[p^1] readers done

    if (u < 31) {      // stage iter u+1 into alternate buffer (full overlap)
      const int un = u + 1;
      const unsigned short* Ab = At[un >> 3] + ((un & 7) << 5);
      const unsigned short* Bb = Bt[un >> 3] + ((un & 7) << 5);
      unsigned short* lA = sm + (p ^ 1) * 4096 + tid * 8;
      unsigned short* lB = sm + (2 + (p ^ 1)) * 4096 + tid * 8;
      gld16(Ab, lA);
      gld16(Ab + 64 * D, lA + 2048);
      gld16(Bb, lB);
      gld16(Bb + 64 * D, lB + 2048);
    }

    const unsigned short* sA = sm + p * 4096;
    const unsigned short* sB = sm + (2 + p) * 4096;
    bf16x8 aF[4], bF[4];
    #pragma unroll
    for (int mt = 0; mt < 4; ++mt)
      aF[mt] = *(const bf16x8*)(sA + (a_row + mt * 16) * 32 + frag_k);
    #pragma unroll
    for (int nt = 0; nt < 4; ++nt)
      bF[nt] = *(const bf16x8*)(sB + (b_row + nt * 16) * 32 + frag_k);
    #pragma unroll
    for (int mt = 0; mt < 4; ++mt)
      #pragma unroll
      for (int nt = 0; nt < 4; ++nt)
        acc[mt][nt] = __builtin_amdgcn_mfma_f32_16x16x32_bf16(
            aF[mt], bF[nt], acc[mt][nt], 0, 0, 0);
  }

  // epilogue: C/D layout col=lane&15, row=quad*4+reg; bias folded here
  float* Yb = Y + (long long)i * BATCH * D;
  const int m0 = bm * 128 + wr * 64 + (q * 4);
  const int n0 = bn * 128 + wc * 64 + (lane & 15);
  float bsum[4];
  #pragma unroll
  for (int nt = 0; nt < 4; ++nt) {
    float s = 0.f;
    for (int t = 0; t < nk; ++t) s += bias[ks[t] * D + n0 + nt * 16];
    bsum[nt] = s;
  }
  #pragma unroll
  for (int nt = 0; nt < 4; ++nt) {
    #pragma unroll
    for (int mt = 0; mt < 4; ++mt)
      #pragma unroll
      for (int r = 0; r < 4; ++r)
        Yb[(long long)(m0 + mt * 16 + r) * D + (n0 + nt * 16)] = acc[mt][nt][r] + bsum[nt];
  }
}

extern "C" void kernel_launch(void* const* d_in, const int* in_sizes, int n_in,
                              void* d_out, int out_size, void* d_ws, size_t ws_size,
                              hipStream_t stream) {
  const float* X = (const float*)d_in[0];
  const float* W = (const float*)d_in[1];
  const float* b = (const float*)d_in[2];
  const int* i_idx = (const int*)d_in[3];
  const int* j_idx = (const int*)d_in[4];
  float* Y = (float*)d_out;
  const int nact = in_sizes[3];   // 48

  // workspace layout: Xb (48 MB bf16) | Wt (6 MB bf16, transposed)
  unsigned short* Xb = (unsigned short*)d_ws;
  unsigned short* Wt = (unsigned short*)((char*)d_ws + (size_t)N_BLOCKS * BATCH * D * 2);

  cvt_x<<<(N_BLOCKS * BATCH * D) / (256 * 8), 256, 0, stream>>>(X, Xb);
  cvt_w<<<nact * 64, 256, 0, stream>>>(W, Wt);
  bs_gemm<<<N_BLOCKS * 64 * 2, 256, 0, stream>>>(Xb, Wt, b, i_idx, j_idx, nact, Y);
}

// Round 4
// 261.860 us; speedup vs baseline: 1.0462x; 1.0371x over previous
//
#include <hip/hip_runtime.h>

#define N_BLOCKS 12
#define D 256
#define BATCH 8192

typedef __attribute__((ext_vector_type(8))) short bf16x8;   // 8 bf16 = 4 VGPRs
typedef __attribute__((ext_vector_type(4))) float f32x4;

// fp32 -> bf16 round-to-nearest-even (bit trick; inputs are finite)
__device__ __forceinline__ unsigned short f2bf(float f) {
  unsigned int u = __float_as_uint(f);
  u += 0x7fffu + ((u >> 16) & 1u);
  return (unsigned short)(u >> 16);
}

// async global->LDS, 16B per lane. LDS dest = wave-uniform base + lane*16.
__device__ __forceinline__ void gld16(const unsigned short* g, unsigned short* l) {
  __builtin_amdgcn_global_load_lds(
      (const __attribute__((address_space(1))) unsigned int*)g,
      (__attribute__((address_space(3))) unsigned int*)l,
      16, 0, 0);
}

// ---------------- Pass 1a: X fp32 -> bf16 (straight copy-convert) ----------
__global__ void cvt_x(const float* __restrict__ X, unsigned short* __restrict__ Xb) {
  const long long t = (long long)blockIdx.x * 256 + threadIdx.x;
  const long long base = t * 8;
  const float4 v0 = *(const float4*)(X + base);
  const float4 v1 = *(const float4*)(X + base + 4);
  uint4 r;
  r.x = (unsigned)f2bf(v0.x) | ((unsigned)f2bf(v0.y) << 16);
  r.y = (unsigned)f2bf(v0.z) | ((unsigned)f2bf(v0.w) << 16);
  r.z = (unsigned)f2bf(v1.x) | ((unsigned)f2bf(v1.y) << 16);
  r.w = (unsigned)f2bf(v1.z) | ((unsigned)f2bf(v1.w) << 16);
  *(uint4*)(Xb + base) = r;
}

// ------------- Pass 1b: W[k][i][o] fp32 -> Wt[k][o][i] bf16 (LDS transpose) -
__global__ void cvt_w(const float* __restrict__ W, unsigned short* __restrict__ Wt) {
  __shared__ unsigned short tile[32][33];   // +1 pad vs bank conflicts
  const int k  = blockIdx.x >> 6;
  const int t  = blockIdx.x & 63;
  const int ti = t >> 3;                    // tile row (i dim), 8 tiles
  const int tj = t & 7;                     // tile col (o dim)
  const float* Wk = W + (long long)k * D * D;
  unsigned short* Wtk = Wt + (long long)k * D * D;
  const int lx = threadIdx.x & 31, ly = threadIdx.x >> 5;   // 32x8
  #pragma unroll
  for (int r = 0; r < 4; ++r) {
    const int i = ti * 32 + ly + r * 8;
    const int o = tj * 32 + lx;
    tile[ly + r * 8][lx] = f2bf(Wk[i * D + o]);
  }
  __syncthreads();
  #pragma unroll
  for (int r = 0; r < 4; ++r) {
    const int o = tj * 32 + ly + r * 8;
    const int i = ti * 32 + lx;
    Wtk[o * D + i] = tile[lx][ly + r * 8];
  }
}

// ------------- Pass 2: block-sparse GEMM, BM=BN=128, BK=32 -----------------
// Per output row i: Y[i] = sum_t Xb[j_t] @ W[k_t] + sum_t b[k_t]
// 4 waves; wave (wr,wc) owns a 64x64 subtile = 4x4 mfma_f32_16x16x32_bf16.
// Round-1 two-barrier K-loop (fastest so far; R2 swizzle + R3 dbuf both lost).
//
// XCD-aware decode: bid&7 -> XCD (round-robin dispatch heuristic). Each XCD
// owns a fixed 8-wide bm-slice for every output row i, with bn adjacent.
// Per-(i,XCD) working set = A-slice 2MB + B 0.5MB < 4MB L2, so the 64x
// B re-stage and the bn-pair A re-stage become L2 hits instead of L3
// traffic (~786 MB -> ~240 MB at L3 level). Theory: staging is L3-BW-bound.
__launch_bounds__(256)
__global__ void bs_gemm(const unsigned short* __restrict__ Xb,
                        const unsigned short* __restrict__ Wt,
                        const float* __restrict__ bias,
                        const int* __restrict__ i_idx,
                        const int* __restrict__ j_idx,
                        int nact,
                        float* __restrict__ Y) {
  __shared__ unsigned short sA[128 * 32];   // A[m][k], k contiguous (8 KB)
  __shared__ unsigned short sB[128 * 32];   // B stored [n][k], k contiguous

  const int bid = blockIdx.x;
  const int x   = bid & 7;         // XCD slot (dispatch round-robin)
  const int r   = bid >> 3;        // 0..191 within XCD
  const int i   = r >> 4;          // output row (12)
  const int rem = r & 15;
  const int bm  = x * 8 + (rem >> 1);   // this XCD's 8-wide bm slice
  const int bn  = rem & 1;

  // collect active blocks feeding output row i (pattern gives 4)
  int ks[8], js[8], nk = 0;
  for (int k = 0; k < nact; ++k)
    if (i_idx[k] == i && nk < 8) { ks[nk] = k; js[nk] = j_idx[k]; ++nk; }

  const int tid  = threadIdx.x;
  const int wave = tid >> 6;
  const int lane = tid & 63;
  const int wr   = wave >> 1, wc = wave & 1;

  // staging: each thread loads 16B; row=tid/4 (stride D), col=(tid&3)*8 elems
  const int g_off = (tid >> 2) * D + (tid & 3) * 8;
  unsigned short* lA0 = sA + tid * 8;
  unsigned short* lA1 = sA + 2048 + tid * 8;   // rows 64..127
  unsigned short* lB0 = sB + tid * 8;
  unsigned short* lB1 = sB + 2048 + tid * 8;

  // fragment read offsets
  const int q      = lane >> 4;                // k-quad
  const int frag_k = q * 8;
  const int a_row  = wr * 64 + (lane & 15);
  const int b_row  = wc * 64 + (lane & 15);

  f32x4 acc[4][4] = {};

  for (int t = 0; t < nk; ++t) {
    const unsigned short* Ab = Xb + ((long long)js[t] * BATCH + bm * 128) * D + g_off;
    const unsigned short* Bb = Wt + ((long long)ks[t] * D + bn * 128) * D + g_off;
    #pragma unroll
    for (int d0 = 0; d0 < D; d0 += 32) {
      gld16(Ab + d0, lA0);
      gld16(Ab + 64 * D + d0, lA1);
      gld16(Bb + d0, lB0);
      gld16(Bb + 64 * D + d0, lB1);
      __syncthreads();   // drains vmcnt: staging complete

      bf16x8 aF[4], bF[4];
      #pragma unroll
      for (int mt = 0; mt < 4; ++mt)
        aF[mt] = *(const bf16x8*)(sA + (a_row + mt * 16) * 32 + frag_k);
      #pragma unroll
      for (int nt = 0; nt < 4; ++nt)
        bF[nt] = *(const bf16x8*)(sB + (b_row + nt * 16) * 32 + frag_k);
      #pragma unroll
      for (int mt = 0; mt < 4; ++mt)
        #pragma unroll
        for (int nt = 0; nt < 4; ++nt)
          acc[mt][nt] = __builtin_amdgcn_mfma_f32_16x16x32_bf16(
              aF[mt], bF[nt], acc[mt][nt], 0, 0, 0);
      __syncthreads();   // all reads done before next staging overwrites
    }
  }

  // epilogue: C/D layout col=lane&15, row=quad*4+reg; bias folded here
  float* Yb = Y + (long long)i * BATCH * D;
  const int m0 = bm * 128 + wr * 64 + (q * 4);
  const int n0 = bn * 128 + wc * 64 + (lane & 15);
  float bsum[4];
  #pragma unroll
  for (int nt = 0; nt < 4; ++nt) {
    float s = 0.f;
    for (int t = 0; t < nk; ++t) s += bias[ks[t] * D + n0 + nt * 16];
    bsum[nt] = s;
  }
  #pragma unroll
  for (int nt = 0; nt < 4; ++nt) {
    #pragma unroll
    for (int mt = 0; mt < 4; ++mt)
      #pragma unroll
      for (int r2 = 0; r2 < 4; ++r2)
        Yb[(long long)(m0 + mt * 16 + r2) * D + (n0 + nt * 16)] = acc[mt][nt][r2] + bsum[nt];
  }
}

extern "C" void kernel_launch(void* const* d_in, const int* in_sizes, int n_in,
                              void* d_out, int out_size, void* d_ws, size_t ws_size,
                              hipStream_t stream) {
  const float* X = (const float*)d_in[0];
  const float* W = (const float*)d_in[1];
  const float* b = (const float*)d_in[2];
  const int* i_idx = (const int*)d_in[3];
  const int* j_idx = (const int*)d_in[4];
  float* Y = (float*)d_out;
  const int nact = in_sizes[3];   // 48

  // workspace layout: Xb (48 MB bf16) | Wt (6 MB bf16, transposed)
  unsigned short* Xb = (unsigned short*)d_ws;
  unsigned short* Wt = (unsigned short*)((char*)d_ws + (size_t)N_BLOCKS * BATCH * D * 2);

  cvt_x<<<(N_BLOCKS * BATCH * D) / (256 * 8), 256, 0, stream>>>(X, Xb);
  cvt_w<<<nact * 64, 256, 0, stream>>>(W, Wt);
  bs_gemm<<<N_BLOCKS * 64 * 2, 256, 0, stream>>>(Xb, Wt, b, i_idx, j_idx, nact, Y);
}